// Round 1
// baseline (180.403 us; speedup 1.0000x reference)
//
#include <hip/hip_runtime.h>

#define NDIM 64
#define KNBR 16
#define NT 18            // curr + dest + 16 neighbors
#define CAP_S1 1024      // max unique layer-1 nodes (expected ~306)
#define CAP_E2 4096      // max layer-2 edges (expected ~288)

// workspace byte offsets
#define OFF_CNT   0                                   // 8 ints (counters)
#define OFF_AGG1  256                                 // CAP_S1*64 floats
#define OFF_AGG2  (OFF_AGG1 + CAP_S1*NDIM*4)          // 32*64 floats
#define ZERO_BYTES (OFF_AGG2 + 32*NDIM*4)             // memset-0 region ends here
#define OFF_TGT   ZERO_BYTES                          // 32 ints (targets)
#define OFF_S1    (OFF_TGT + 128)                     // CAP_S1 ints (slot -> node)
#define OFF_E2    (OFF_S1 + CAP_S1*4)                 // CAP_E2 ints (packed e*32+k)
#define OFF_H     (OFF_E2 + CAP_E2*4)                 // CAP_S1*64 floats (layer-1 h)
#define OFF_OUTH  (OFF_H + CAP_S1*NDIM*4)             // 32*64 floats (layer-2 out)
#define OFF_SLOT  (OFF_OUTH + 32*NDIM*4)              // N ints (node -> slot, memset 0xFF)

__device__ __forceinline__ int imin(int a, int b) { return a < b ? a : b; }

// Pass A: read the 18 target node ids, claim S1 slots for them (serial => dedup'd).
__global__ void k_init(const int* curr, const int* dest, const int* nbr,
                       int* cnt, int* tgt, int* s1list, int* slotOf) {
    if (blockIdx.x == 0 && threadIdx.x == 0) {
        int t[NT];
        t[0] = curr[0];
        t[1] = dest[0];
        for (int j = 0; j < KNBR; ++j) t[2 + j] = nbr[j];
        int n = 0;
        for (int i = 0; i < NT; ++i) {
            tgt[i] = t[i];
            int v = t[i];
            if (slotOf[v] < 0) { slotOf[v] = n; s1list[n] = v; ++n; }
        }
        cnt[0] = n;   // nS1 so far
    }
}

// Pass B: scan all edges; record edges whose dst is a target (layer-2 edges),
// and claim S1 slots for their source nodes.
__global__ void k_scan2(const int* __restrict__ src, const int* __restrict__ dst, int E,
                        const int* __restrict__ tgt, int* cnt, int* slotOf,
                        int* s1list, int* edges2) {
    __shared__ int tg[NT];
    if (threadIdx.x < NT) tg[threadIdx.x] = tgt[threadIdx.x];
    __syncthreads();
    int stride = gridDim.x * blockDim.x;
    for (int e = blockIdx.x * blockDim.x + threadIdx.x; e < E; e += stride) {
        int d = dst[e];
        bool any = false;
        #pragma unroll
        for (int k = 0; k < NT; ++k) {
            if (d == tg[k]) {
                any = true;
                int idx = atomicAdd(&cnt[2], 1);
                if (idx < CAP_E2) edges2[idx] = e * 32 + k;   // pack (e,k)
            }
        }
        if (any) {
            int v = src[e];
            int prev = atomicCAS(&slotOf[v], -1, -2);   // claim once
            if (prev == -1) {
                int s = atomicAdd(&cnt[0], 1);
                if (s < CAP_S1) s1list[s] = v;
                __threadfence();
                slotOf[v] = s;
            }
        }
    }
}

// Pass C: scan all edges; for edges whose dst is in S1, compute the layer-1
// message relu(x[src] + a*We1 + be1) and atomically accumulate into agg1[slot].
__global__ void k_scan_agg1(const int* __restrict__ src, const int* __restrict__ dst, int E,
                            const int* __restrict__ slotOf, const float* __restrict__ x,
                            const float* __restrict__ eattr,
                            const float* __restrict__ We1, const float* __restrict__ be1,
                            float* agg1) {
    int stride = gridDim.x * blockDim.x;
    for (int e = blockIdx.x * blockDim.x + threadIdx.x; e < E; e += stride) {
        int s = slotOf[dst[e]];
        if (s >= 0 && s < CAP_S1) {
            int v = src[e];
            float a = eattr[e];
            const float4* xr = (const float4*)(x + (size_t)v * NDIM);
            const float4* w  = (const float4*)We1;
            const float4* b  = (const float4*)be1;
            float* ag = agg1 + (size_t)s * NDIM;
            #pragma unroll
            for (int r = 0; r < NDIM / 4; ++r) {
                float4 xv = xr[r], wv = w[r], bv = b[r];
                atomicAdd(&ag[4*r+0], fmaxf(fmaf(a, wv.x, xv.x + bv.x), 0.f));
                atomicAdd(&ag[4*r+1], fmaxf(fmaf(a, wv.y, xv.y + bv.y), 0.f));
                atomicAdd(&ag[4*r+2], fmaxf(fmaf(a, wv.z, xv.z + bv.z), 0.f));
                atomicAdd(&ag[4*r+3], fmaxf(fmaf(a, wv.w, xv.w + bv.w), 0.f));
            }
        }
    }
}

// Pass D: layer-1 MLP at each S1 node: h = relu(relu((x+agg1)@W1a+b1a)@W1b+b1b)
__global__ void k_mlp1(const int* cnt, const int* s1list, const float* __restrict__ x,
                       const float* __restrict__ agg1,
                       const float* __restrict__ W1a, const float* __restrict__ b1a,
                       const float* __restrict__ W1b, const float* __restrict__ b1b,
                       float* hbuf) {
    int s = blockIdx.x;
    if (s >= imin(cnt[0], CAP_S1)) return;
    int d = threadIdx.x;
    __shared__ float t[NDIM], u[NDIM];
    int v = s1list[s];
    t[d] = x[(size_t)v * NDIM + d] + agg1[(size_t)s * NDIM + d];
    __syncthreads();
    float acc = b1a[d];
    #pragma unroll
    for (int k = 0; k < NDIM; ++k) acc = fmaf(t[k], W1a[k * NDIM + d], acc);
    u[d] = fmaxf(acc, 0.f);
    __syncthreads();
    float acc2 = b1b[d];
    #pragma unroll
    for (int k = 0; k < NDIM; ++k) acc2 = fmaf(u[k], W1b[k * NDIM + d], acc2);
    hbuf[(size_t)s * NDIM + d] = fmaxf(acc2, 0.f);
}

// Pass E: layer-2 aggregation over the recorded edges into agg2[targetSlot].
__global__ void k_agg2(const int* __restrict__ edges2, const int* cnt,
                       const int* __restrict__ src, const float* __restrict__ eattr,
                       const int* __restrict__ slotOf, const float* __restrict__ hbuf,
                       const float* __restrict__ We2, const float* __restrict__ be2,
                       float* agg2) {
    int n = imin(cnt[2], CAP_E2) * NDIM;
    int stride = gridDim.x * blockDim.x;
    for (int i = blockIdx.x * blockDim.x + threadIdx.x; i < n; i += stride) {
        int li = i >> 6, d = i & 63;
        int pk = edges2[li];
        int e = pk >> 5, k = pk & 31;
        int s = slotOf[src[e]];
        if (s < 0 || s >= CAP_S1) continue;
        float m = fmaxf(hbuf[(size_t)s * NDIM + d] + fmaf(eattr[e], We2[d], be2[d]), 0.f);
        atomicAdd(&agg2[k * NDIM + d], m);
    }
}

// Pass F: layer-2 MLP at the 18 targets (no final relu).
__global__ void k_mlp2(const int* tgt, const int* __restrict__ slotOf,
                       const float* __restrict__ hbuf, const float* __restrict__ agg2,
                       const float* __restrict__ W2a, const float* __restrict__ b2a,
                       const float* __restrict__ W2b, const float* __restrict__ b2b,
                       float* outh) {
    int k = blockIdx.x;     // 0..17
    int d = threadIdx.x;
    __shared__ float t[NDIM], u[NDIM];
    int v = tgt[k];
    int s = slotOf[v];
    t[d] = hbuf[(size_t)s * NDIM + d] + agg2[k * NDIM + d];
    __syncthreads();
    float acc = b2a[d];
    #pragma unroll
    for (int kk = 0; kk < NDIM; ++kk) acc = fmaf(t[kk], W2a[kk * NDIM + d], acc);
    u[d] = fmaxf(acc, 0.f);
    __syncthreads();
    float acc2 = b2b[d];
    #pragma unroll
    for (int kk = 0; kk < NDIM; ++kk) acc2 = fmaf(u[kk], W2b[kk * NDIM + d], acc2);
    outh[k * NDIM + d] = acc2;
}

// Pass G: Q head: q[j] = relu([curr,dest,nbr_j] @ Wl1 + bl1) @ Wl2 + bl2
__global__ void k_q(const float* __restrict__ outh,
                    const float* __restrict__ Wl1, const float* __restrict__ bl1,
                    const float* __restrict__ Wl2, const float* __restrict__ bl2,
                    float* out) {
    int j = blockIdx.x;     // 0..15
    int d = threadIdx.x;    // 0..63, one wave
    const float* c0 = outh;                 // curr  (k=0)
    const float* c1 = outh + NDIM;          // dest  (k=1)
    const float* cn = outh + (2 + j) * NDIM;
    float acc = bl1[d];
    #pragma unroll
    for (int i = 0; i < NDIM; ++i) acc = fmaf(c0[i], Wl1[i * NDIM + d], acc);
    #pragma unroll
    for (int i = 0; i < NDIM; ++i) acc = fmaf(c1[i], Wl1[(NDIM + i) * NDIM + d], acc);
    #pragma unroll
    for (int i = 0; i < NDIM; ++i) acc = fmaf(cn[i], Wl1[(2 * NDIM + i) * NDIM + d], acc);
    acc = fmaxf(acc, 0.f) * Wl2[d];
    #pragma unroll
    for (int off = 32; off > 0; off >>= 1) acc += __shfl_down(acc, off);
    if (d == 0) out[j] = acc + bl2[0];
}

extern "C" void kernel_launch(void* const* d_in, const int* in_sizes, int n_in,
                              void* d_out, int out_size, void* d_ws, size_t ws_size,
                              hipStream_t stream) {
    const float* x     = (const float*)d_in[0];
    const int*   eidx  = (const int*)d_in[1];
    const int    E     = in_sizes[1] / 2;
    const int    Nn    = in_sizes[0] / NDIM;
    const int*   src   = eidx;
    const int*   dstA  = eidx + E;
    const int*   curr  = (const int*)d_in[2];
    const int*   dest  = (const int*)d_in[3];
    const int*   nbr   = (const int*)d_in[4];
    const float* eattr = (const float*)d_in[5];
    const float* We1 = (const float*)d_in[6];
    const float* be1 = (const float*)d_in[7];
    const float* W1a = (const float*)d_in[8];
    const float* b1a = (const float*)d_in[9];
    const float* W1b = (const float*)d_in[10];
    const float* b1b = (const float*)d_in[11];
    const float* We2 = (const float*)d_in[12];
    const float* be2 = (const float*)d_in[13];
    const float* W2a = (const float*)d_in[14];
    const float* b2a = (const float*)d_in[15];
    const float* W2b = (const float*)d_in[16];
    const float* b2b = (const float*)d_in[17];
    const float* Wl1 = (const float*)d_in[18];
    const float* bl1 = (const float*)d_in[19];
    const float* Wl2 = (const float*)d_in[20];
    const float* bl2 = (const float*)d_in[21];

    char* ws = (char*)d_ws;
    int*   cnt    = (int*)(ws + OFF_CNT);
    float* agg1   = (float*)(ws + OFF_AGG1);
    float* agg2   = (float*)(ws + OFF_AGG2);
    int*   tgt    = (int*)(ws + OFF_TGT);
    int*   s1list = (int*)(ws + OFF_S1);
    int*   edges2 = (int*)(ws + OFF_E2);
    float* hbuf   = (float*)(ws + OFF_H);
    float* outh   = (float*)(ws + OFF_OUTH);
    int*   slotOf = (int*)(ws + OFF_SLOT);

    // init: counters + agg buffers to 0, slotOf to -1
    hipMemsetAsync(ws, 0, ZERO_BYTES, stream);
    hipMemsetAsync(ws + OFF_SLOT, 0xFF, (size_t)Nn * 4, stream);

    k_init<<<1, 64, 0, stream>>>(curr, dest, nbr, cnt, tgt, s1list, slotOf);
    k_scan2<<<1024, 256, 0, stream>>>(src, dstA, E, tgt, cnt, slotOf, s1list, edges2);
    k_scan_agg1<<<1024, 256, 0, stream>>>(src, dstA, E, slotOf, x, eattr, We1, be1, agg1);
    k_mlp1<<<CAP_S1, 64, 0, stream>>>(cnt, s1list, x, agg1, W1a, b1a, W1b, b1b, hbuf);
    k_agg2<<<64, 256, 0, stream>>>(edges2, cnt, src, eattr, slotOf, hbuf, We2, be2, agg2);
    k_mlp2<<<NT, 64, 0, stream>>>(tgt, slotOf, hbuf, agg2, W2a, b2a, W2b, b2b, outh);
    k_q<<<KNBR, 64, 0, stream>>>(outh, Wl1, bl1, Wl2, bl2, (float*)d_out);
}